// Round 1
// baseline (204.387 us; speedup 1.0000x reference)
//
#include <hip/hip_runtime.h>
#include <stdint.h>

// Problem constants (fixed by the reference file)
#define T_TOTAL  4194304          // B*K*N = 8*4*131072
#define NEG_IDLE (-100000000.0f)
#define NEG_FILL (-1000.0f)

#define BLOCK   256
#define EPT     8
#define EPB     (BLOCK * EPT)       // 2048 elements per block
#define NBLOCKS (T_TOTAL / EPB)     // 2048 blocks
// N = 131072 = 64 * 2048 -> each block has one uniform (b,k): bk = blk >> 6

// Workspace layout:
//   [0 .. 16K)      : sums[2048]  u64 packed (surf count low32, air high32)
//   [16K .. 16K+1M) : packed bits, u16 per thread (surf low8 | air<<8)
// K1 fully writes both regions before K2 reads them (stream order), so the
// 0xAA re-poison of d_ws needs no separate init kernel.

typedef unsigned int u32x4 __attribute__((ext_vector_type(4)));

// 8 consecutive int32 bool elements -> 8-bit mask (jnp bool arrives as int32)
__device__ __forceinline__ unsigned decode8_i32(const u32x4 a, const u32x4 b) {
    return (a.x ? 1u : 0u) | (a.y ? 2u : 0u) | (a.z ? 4u : 0u) | (a.w ? 8u : 0u)
         | (b.x ? 16u : 0u) | (b.y ? 32u : 0u) | (b.z ? 64u : 0u) | (b.w ? 128u : 0u);
}

// ---------------------------------------------------------------------------
// Kernel 1: per-block mask popcounts + bit-repack (1 barrier).
// Masks are read-once 32 MB -> nontemporal so they don't churn L2.
// ---------------------------------------------------------------------------
__global__ __launch_bounds__(BLOCK) void reduce_pack_kernel(
    const u32x4* __restrict__ ms,
    const u32x4* __restrict__ ma,
    unsigned long long* __restrict__ sums,
    unsigned short* __restrict__ packed)
{
    const int blk  = blockIdx.x;
    const int tid  = threadIdx.x;
    const int lane = tid & 63;
    const int wave = tid >> 6;
    const size_t e = (size_t)blk * EPB + (size_t)tid * EPT;

    const u32x4* ps = ms + (e >> 2);
    const u32x4* pa = ma + (e >> 2);
    const u32x4 s0 = __builtin_nontemporal_load(ps);
    const u32x4 s1 = __builtin_nontemporal_load(ps + 1);
    const u32x4 a0 = __builtin_nontemporal_load(pa);
    const u32x4 a1 = __builtin_nontemporal_load(pa + 1);
    const unsigned bits_s = decode8_i32(s0, s1);
    const unsigned bits_a = decode8_i32(a0, a1);
    packed[blk * BLOCK + tid] = (unsigned short)(bits_s | (bits_a << 8));

    unsigned long long v =
        ((unsigned long long)(unsigned)__popc(bits_a) << 32) | (unsigned)__popc(bits_s);
    #pragma unroll
    for (int d = 32; d; d >>= 1) v += __shfl_down(v, d, 64);

    __shared__ unsigned long long w[BLOCK / 64];
    if (lane == 0) w[wave] = v;
    __syncthreads();
    if (tid == 0) sums[blk] = w[0] + w[1] + w[2] + w[3];
}

// ---------------------------------------------------------------------------
// Kernel 2: BARRIER-FREE. Each wave independently computes its global prefix:
//   - whole-slice reduction of sums[0..blk-1] (32 u64 per lane, L1-hot 16 KB)
//   - prior waves of this block re-counted from packed[] (<=3 u16/lane, L1-hot)
//   - one shfl_xor butterfly all-reduce folds both; wave-scan gives per-lane base.
// No LDS, no __syncthreads: gathers issue as soon as a wave's own scan is done.
// ---------------------------------------------------------------------------
__global__ __launch_bounds__(BLOCK) void scatter_kernel(
    const float* __restrict__ rgb,
    const float* __restrict__ ls,
    const float* __restrict__ la,
    const unsigned long long* __restrict__ sums,
    const unsigned short* __restrict__ packed,
    const float* __restrict__ idle_states,
    float* __restrict__ out)
{
    const int blk  = blockIdx.x;
    const int tid  = threadIdx.x;
    const int lane = tid & 63;
    const int wave = tid >> 6;
    const size_t base = (size_t)blk * EPB + (size_t)tid * EPT;

    // ---- masks ----
    const unsigned p = packed[blk * BLOCK + tid];
    const unsigned bits_s = p & 0xffu;
    const unsigned bits_a = p >> 8;

    // ---- global prefix: each WAVE reduces the full sums[0..blk-1] slice ----
    // lane l covers u64 indices [32l, 32l+32): 16x dwordx4, 16 KB L1-resident.
    unsigned long long acc = 0;
    {
        const ulonglong2* s2 = (const ulonglong2*)sums;
        const int i0 = lane * 32;
        #pragma unroll
        for (int q = 0; q < 16; ++q) {
            const ulonglong2 v = s2[lane * 16 + q];
            const int i = i0 + 2 * q;
            acc += (i     < blk) ? v.x : 0ull;
            acc += (i + 1 < blk) ? v.y : 0ull;
        }
    }
    // ---- prior waves of this block, re-counted from packed (wave-uniform) ----
    #pragma unroll
    for (int w = 0; w < BLOCK / 64 - 1; ++w) {
        if (w < wave) {
            const unsigned pp = packed[blk * BLOCK + w * 64 + lane];
            acc += ((unsigned long long)(unsigned)__popc(pp >> 8) << 32)
                 | (unsigned)__popc(pp & 0xffu);
        }
    }
    // butterfly all-reduce: every lane gets (blocks < blk) + (waves < wave)
    #pragma unroll
    for (int d = 32; d; d >>= 1) acc += __shfl_xor(acc, d, 64);

    // ---- wave-level inclusive scan of packed (air<<32 | surf) counts ----
    const unsigned long long pk =
        ((unsigned long long)(unsigned)__popc(bits_a) << 32) | (unsigned)__popc(bits_s);
    unsigned long long incl = pk;
    #pragma unroll
    for (int d = 1; d < 64; d <<= 1) {
        unsigned long long t = __shfl_up(incl, d, 64);
        if (lane >= d) incl += t;
    }
    const unsigned long long start = acc + (incl - pk);

    const int idx_s0 = (int)(start & 0xffffffffULL);
    const int idx_a0 = (int)(start >> 32);

    // ---- per-element indices, branch-free, no serial chain ----
    int is_[EPT], ia_[EPT];
    #pragma unroll
    for (int j = 0; j < EPT; ++j) {
        is_[j] = idx_s0 + __popc(bits_s & ((1u << j) - 1u));
        ia_[j] = idx_a0 + __popc(bits_a & ((1u << j) - 1u));
    }

    // ---- issue all gathers (always in-bounds: excl prefix <= elem pos < T) ----
    float r[3 * EPT], sv[EPT], av[EPT];
    #pragma unroll
    for (int j = 0; j < EPT; ++j) {
        const float* rp = rgb + (size_t)is_[j] * 3;
        r[3 * j + 0] = rp[0];
        r[3 * j + 1] = rp[1];
        r[3 * j + 2] = rp[2];
        sv[j] = ls[is_[j]];
        av[j] = la[ia_[j]];
    }

    // ---- select/scale ----
    const float idle      = idle_states[blk >> 6];   // uniform per block
    const float scale     = 1.0f - idle;
    const float idle_term = idle * NEG_IDLE;
    #pragma unroll
    for (int j = 0; j < EPT; ++j) {
        const bool bs = (bits_s >> j) & 1u;
        const bool ba = (bits_a >> j) & 1u;
        r[3 * j + 0] = bs ? r[3 * j + 0] * scale : 0.0f;
        r[3 * j + 1] = bs ? r[3 * j + 1] * scale : 0.0f;
        r[3 * j + 2] = bs ? r[3 * j + 2] * scale : 0.0f;
        sv[j] = bs ? (sv[j] * scale + idle_term) : NEG_FILL;
        av[j] = ba ? (av[j] * scale + idle_term) : NEG_FILL;
    }

    // ---- vectorized stores (per-thread contiguous, 16B-aligned; block covers
    // its whole output region, so L2 merges the stride-96/stride-32 partials
    // into full lines before HBM) ----
    float4* prgb = (float4*)(out + base * 3);                    // 96 B/thread
    #pragma unroll
    for (int j = 0; j < 6; ++j) prgb[j] = ((const float4*)r)[j];

    float4* pls = (float4*)(out + (size_t)3 * T_TOTAL + base);   // 32 B/thread
    pls[0] = ((const float4*)sv)[0];
    pls[1] = ((const float4*)sv)[1];

    float4* pla = (float4*)(out + (size_t)4 * T_TOTAL + base);
    pla[0] = ((const float4*)av)[0];
    pla[1] = ((const float4*)av)[1];
}

// ---------------------------------------------------------------------------
extern "C" void kernel_launch(void* const* d_in, const int* in_sizes, int n_in,
                              void* d_out, int out_size, void* d_ws, size_t ws_size,
                              hipStream_t stream) {
    const float* rgb  = (const float*)d_in[0];
    const float* ls   = (const float*)d_in[1];
    const float* la   = (const float*)d_in[2];
    const u32x4* ms   = (const u32x4*)d_in[3];   // jnp bool -> int32 on device
    const u32x4* ma   = (const u32x4*)d_in[4];
    const float* idle = (const float*)d_in[5];
    float* out = (float*)d_out;

    unsigned long long* sums   = (unsigned long long*)d_ws;
    unsigned short*     packed = (unsigned short*)((uint8_t*)d_ws + NBLOCKS * sizeof(unsigned long long));

    reduce_pack_kernel<<<NBLOCKS, BLOCK, 0, stream>>>(ms, ma, sums, packed);
    scatter_kernel<<<NBLOCKS, BLOCK, 0, stream>>>(rgb, ls, la, sums, packed,
                                                  idle, out);
}

// Round 3
// 172.989 us; speedup vs baseline: 1.1815x; 1.1815x over previous
//
#include <hip/hip_runtime.h>
#include <stdint.h>

// Problem constants (fixed by the reference file)
#define T_TOTAL  4194304          // B*K*N = 8*4*131072
#define NEG_IDLE (-100000000.0f)
#define NEG_FILL (-1000.0f)

#define BLOCK   256
#define EPT     8
#define EPB     (BLOCK * EPT)       // 2048 elements per block
#define NBLOCKS (T_TOTAL / EPB)     // 2048 blocks
// N = 131072 = 64 * 2048 -> each block has one uniform (b,k): bk = blk >> 6

// LDS pad-swizzle: +1 dword per 32 (breaks power-of-2 bank aliasing)
#define SWZ(d) ((d) + ((d) >> 5))

typedef unsigned int u32x4 __attribute__((ext_vector_type(4)));
typedef float        f32x4 __attribute__((ext_vector_type(4)));

// 8 consecutive int32 bool elements -> 8-bit mask (jnp bool arrives as int32)
__device__ __forceinline__ unsigned decode8_i32(const u32x4 a, const u32x4 b) {
    return (a.x ? 1u : 0u) | (a.y ? 2u : 0u) | (a.z ? 4u : 0u) | (a.w ? 8u : 0u)
         | (b.x ? 16u : 0u) | (b.y ? 32u : 0u) | (b.z ? 64u : 0u) | (b.w ? 128u : 0u);
}

__device__ __forceinline__ f32x4 mk4(float a, float b, float c, float d) {
    f32x4 v; v.x = a; v.y = b; v.z = c; v.w = d; return v;
}

// ---------------------------------------------------------------------------
// Kernel 1: per-block mask popcounts + bit-repack (1 barrier). Masks are
// read-once 32 MB -> nontemporal.
// ---------------------------------------------------------------------------
__global__ __launch_bounds__(BLOCK) void reduce_pack_kernel(
    const u32x4* __restrict__ ms,
    const u32x4* __restrict__ ma,
    unsigned long long* __restrict__ sums,
    unsigned short* __restrict__ packed)
{
    const int blk  = blockIdx.x;
    const int tid  = threadIdx.x;
    const int lane = tid & 63;
    const int wave = tid >> 6;
    const size_t e = (size_t)blk * EPB + (size_t)tid * EPT;

    const u32x4* ps = ms + (e >> 2);
    const u32x4* pa = ma + (e >> 2);
    const u32x4 s0 = __builtin_nontemporal_load(ps);
    const u32x4 s1 = __builtin_nontemporal_load(ps + 1);
    const u32x4 a0 = __builtin_nontemporal_load(pa);
    const u32x4 a1 = __builtin_nontemporal_load(pa + 1);
    const unsigned bits_s = decode8_i32(s0, s1);
    const unsigned bits_a = decode8_i32(a0, a1);
    packed[blk * BLOCK + tid] = (unsigned short)(bits_s | (bits_a << 8));

    unsigned long long v =
        ((unsigned long long)(unsigned)__popc(bits_a) << 32) | (unsigned)__popc(bits_s);
    #pragma unroll
    for (int d = 32; d; d >>= 1) v += __shfl_down(v, d, 64);

    __shared__ unsigned long long w[BLOCK / 64];
    if (lane == 0) w[wave] = v;
    __syncthreads();
    if (tid == 0) sums[blk] = w[0] + w[1] + w[2] + w[3];
}

// ---------------------------------------------------------------------------
// Kernel 2: block prefix (round-0 distributed scheme) + LDS-staged gathers.
// The block's compacted surface range [start_s, start_s+cnt_s) is CONTIGUOUS:
//   - stage rgb (3*cnt dwords) and ls (cnt dwords) into LDS with coalesced
//     predicated loads (all in flight), swizzled d+(d>>5);
//   - per-element gathers become LDS reads (was: ~50-line divergent VMEM);
//   - rgb output transposed through the SAME LDS buffer -> coalesced float4
//     stores (was: 96B/lane stride = 64 lines per store instruction).
// la gathers + ls/la stores stay direct (moderate divergence).
// ---------------------------------------------------------------------------
__global__ __launch_bounds__(BLOCK) void scatter_kernel(
    const float* __restrict__ rgb,
    const float* __restrict__ ls,
    const float* __restrict__ la,
    const unsigned long long* __restrict__ sums,
    const unsigned short* __restrict__ packed,
    const float* __restrict__ idle_states,
    float* __restrict__ out)
{
    // SWZ(6146)=6338 max touched (incl. discarded masked-off reads) -> 6340
    __shared__ float rgbb[6340];                 // 25360 B, reused for output
    __shared__ float lsb[2120];                  // 8480 B
    __shared__ unsigned long long wtot[BLOCK / 64];
    __shared__ unsigned long long wpre[BLOCK / 64];

    const int blk  = blockIdx.x;
    const int tid  = threadIdx.x;
    const int lane = tid & 63;
    const int wave = tid >> 6;

    // ---- masks + own-block totals ----
    const unsigned p = packed[blk * BLOCK + tid];
    const unsigned bits_s = p & 0xffu;
    const unsigned bits_a = p >> 8;
    const int cnt_s = (int)(unsigned)(sums[blk] & 0xffffffffu);

    // ---- block prefix: thread t covers sums[8t..8t+8) (16 KB, L2-hot) ----
    unsigned long long acc = 0;
    {
        const ulonglong2* s2 = (const ulonglong2*)sums;
        const int i0 = tid * 8;
        #pragma unroll
        for (int q = 0; q < 4; ++q) {
            const ulonglong2 v = s2[tid * 4 + q];
            const int i = i0 + 2 * q;
            acc += (i     < blk) ? v.x : 0ull;
            acc += (i + 1 < blk) ? v.y : 0ull;
        }
        #pragma unroll
        for (int d = 32; d; d >>= 1) acc += __shfl_down(acc, d, 64);
    }

    // ---- wave-level inclusive scan of packed (air<<32 | surf) counts ----
    const unsigned long long pk =
        ((unsigned long long)(unsigned)__popc(bits_a) << 32) | (unsigned)__popc(bits_s);
    unsigned long long incl = pk;
    #pragma unroll
    for (int d = 1; d < 64; d <<= 1) {
        unsigned long long t = __shfl_up(incl, d, 64);
        if (lane >= d) incl += t;
    }
    unsigned long long excl = incl - pk;

    if (lane == 63) wtot[wave] = incl;
    if (lane == 0)  wpre[wave] = acc;
    __syncthreads();
    #pragma unroll
    for (int w = 0; w < BLOCK / 64; ++w)
        if (w < wave) excl += wtot[w];
    const unsigned long long pre = wpre[0] + wpre[1] + wpre[2] + wpre[3];
    const unsigned long long st  = pre + excl;   // low32 can't carry into high32

    const int start_s = (int)(unsigned)(pre & 0xffffffffu);   // block's surf base
    const int idx_a0  = (int)(st >> 32);                      // global air idx
    const int loc_s0  = (int)(unsigned)(st & 0xffffffffu) - start_s; // in-block

    // ---- per-element indices (local for surf, global for air) ----
    int ls_[EPT], ia_[EPT];
    #pragma unroll
    for (int j = 0; j < EPT; ++j) {
        ls_[j] = loc_s0 + __popc(bits_s & ((1u << j) - 1u));
        ia_[j] = idx_a0 + __popc(bits_a & ((1u << j) - 1u));
    }

    // ---- issue la gathers early (latency hides under staging) ----
    float av[EPT];
    #pragma unroll
    for (int j = 0; j < EPT; ++j) av[j] = la[ia_[j]];

    // ---- stage rgb + ls ranges into LDS: coalesced, all loads in flight ----
    const float* rgb_g = rgb + (size_t)start_s * 3;
    const float* ls_g  = ls + start_s;
    const int c3 = cnt_s * 3;                    // <= 6144
    float t24[24], t8[8];
    #pragma unroll
    for (int q = 0; q < 24; ++q) {
        const int d = tid + 256 * q;
        t24[q] = (d < c3) ? __builtin_nontemporal_load(rgb_g + d) : 0.0f;
    }
    #pragma unroll
    for (int q = 0; q < 8; ++q) {
        const int d = tid + 256 * q;
        t8[q] = (d < cnt_s) ? __builtin_nontemporal_load(ls_g + d) : 0.0f;
    }
    #pragma unroll
    for (int q = 0; q < 24; ++q) {
        const int d = tid + 256 * q;
        if (d < c3) rgbb[SWZ(d)] = t24[q];
    }
    #pragma unroll
    for (int q = 0; q < 8; ++q) {
        const int d = tid + 256 * q;
        if (d < cnt_s) lsb[SWZ(d)] = t8[q];
    }
    __syncthreads();

    // ---- LDS gathers (masked-off lanes read garbage, value discarded) ----
    float r[3 * EPT], sv[EPT];
    #pragma unroll
    for (int j = 0; j < EPT; ++j) {
        const int b = ls_[j] * 3;
        r[3 * j + 0] = rgbb[SWZ(b)];
        r[3 * j + 1] = rgbb[SWZ(b + 1)];
        r[3 * j + 2] = rgbb[SWZ(b + 2)];
        sv[j] = lsb[SWZ(ls_[j])];
    }
    __syncthreads();   // all rgbb reads done; buffer reused for output below

    // ---- select/scale ----
    const float idle      = idle_states[blk >> 6];   // uniform per block
    const float scale     = 1.0f - idle;
    const float idle_term = idle * NEG_IDLE;
    #pragma unroll
    for (int j = 0; j < EPT; ++j) {
        const bool bs = (bits_s >> j) & 1u;
        const bool ba = (bits_a >> j) & 1u;
        r[3 * j + 0] = bs ? r[3 * j + 0] * scale : 0.0f;
        r[3 * j + 1] = bs ? r[3 * j + 1] * scale : 0.0f;
        r[3 * j + 2] = bs ? r[3 * j + 2] * scale : 0.0f;
        sv[j] = bs ? (sv[j] * scale + idle_term) : NEG_FILL;
        av[j] = ba ? (av[j] * scale + idle_term) : NEG_FILL;
    }

    // ---- ls/la stores direct (32B/thread, nontemporal) ----
    const size_t base = (size_t)blk * EPB + (size_t)tid * EPT;
    {
        f32x4* pls = (f32x4*)(out + (size_t)3 * T_TOTAL + base);
        __builtin_nontemporal_store(mk4(sv[0], sv[1], sv[2], sv[3]), pls);
        __builtin_nontemporal_store(mk4(sv[4], sv[5], sv[6], sv[7]), pls + 1);
        f32x4* pla = (f32x4*)(out + (size_t)4 * T_TOTAL + base);
        __builtin_nontemporal_store(mk4(av[0], av[1], av[2], av[3]), pla);
        __builtin_nontemporal_store(mk4(av[4], av[5], av[6], av[7]), pla + 1);
    }

    // ---- rgb output transpose: regs -> LDS (swizzled) -> coalesced float4 ----
    #pragma unroll
    for (int j = 0; j < 3 * EPT; ++j) {
        const int e = tid * 24 + j;              // this thread's 24 out dwords
        rgbb[SWZ(e)] = r[j];
    }
    __syncthreads();
    float* out_rgb = out + (size_t)blk * (EPB * 3);
    #pragma unroll
    for (int i = 0; i < 6; ++i) {
        const int g = tid * 4 + 1024 * i;        // lane-consecutive 16B chunks
        const f32x4 v = mk4(rgbb[SWZ(g)], rgbb[SWZ(g + 1)],
                            rgbb[SWZ(g + 2)], rgbb[SWZ(g + 3)]);
        __builtin_nontemporal_store(v, (f32x4*)(out_rgb + g));
    }
}

// ---------------------------------------------------------------------------
extern "C" void kernel_launch(void* const* d_in, const int* in_sizes, int n_in,
                              void* d_out, int out_size, void* d_ws, size_t ws_size,
                              hipStream_t stream) {
    const float* rgb  = (const float*)d_in[0];
    const float* ls   = (const float*)d_in[1];
    const float* la   = (const float*)d_in[2];
    const u32x4* ms   = (const u32x4*)d_in[3];   // jnp bool -> int32 on device
    const u32x4* ma   = (const u32x4*)d_in[4];
    const float* idle = (const float*)d_in[5];
    float* out = (float*)d_out;

    unsigned long long* sums   = (unsigned long long*)d_ws;
    unsigned short*     packed = (unsigned short*)((uint8_t*)d_ws + NBLOCKS * sizeof(unsigned long long));

    reduce_pack_kernel<<<NBLOCKS, BLOCK, 0, stream>>>(ms, ma, sums, packed);
    scatter_kernel<<<NBLOCKS, BLOCK, 0, stream>>>(rgb, ls, la, sums, packed,
                                                  idle, out);
}